// Round 2
// baseline (612.214 us; speedup 1.0000x reference)
//
#include <hip/hip_runtime.h>
#include <hip/hip_bf16.h>
#include <cstdint>

// B=2, HW=64 -> 128 rows of S=256; M = 32768. D=512, HEADS=8, DK=64,
// 3*H*DK=1536, KSIZE=7. Inputs/outputs are float32 on device (per reference);
// internal compute uses bf16 MFMA (2%-relative threshold permits it).

typedef __bf16 bf16x8 __attribute__((ext_vector_type(8)));
typedef float f32x4 __attribute__((ext_vector_type(4)));

__device__ __forceinline__ uint16_t f2bf(float f) {
    uint32_t u = __builtin_bit_cast(uint32_t, f);
    return (uint16_t)((u + 0x7fffu + ((u >> 16) & 1u)) >> 16);
}
__device__ __forceinline__ float bflo(uint32_t u) { return __builtin_bit_cast(float, u << 16); }
__device__ __forceinline__ float bfhi(uint32_t u) { return __builtin_bit_cast(float, u & 0xffff0000u); }

__device__ __forceinline__ void unpack8(uint4 v, float* f) {
    f[0] = bflo(v.x); f[1] = bfhi(v.x);
    f[2] = bflo(v.y); f[3] = bfhi(v.y);
    f[4] = bflo(v.z); f[5] = bfhi(v.z);
    f[6] = bflo(v.w); f[7] = bfhi(v.w);
}
__device__ __forceinline__ uint32_t pack2(float a, float b) {
    return (uint32_t)f2bf(a) | ((uint32_t)f2bf(b) << 16);
}

#define GLOAD_LDS16(gp, lp)                                                        \
    __builtin_amdgcn_global_load_lds((const __attribute__((address_space(1))) void*)(gp), \
                                     (__attribute__((address_space(3))) void*)(lp), 16, 0, 0)

// ---------------------------------------------------------------------------
// fp32 -> bf16 bulk convert, 8 elems/thread
// ---------------------------------------------------------------------------
__global__ void cvt_f32_bf16(const float* __restrict__ in, uint16_t* __restrict__ out, int n8) {
    int i = blockIdx.x * 256 + threadIdx.x;
    if (i >= n8) return;
    const float4* p = (const float4*)in + (size_t)i * 2;
    float4 a = p[0], b = p[1];
    uint4 o;
    o.x = pack2(a.x, a.y);
    o.y = pack2(a.z, a.w);
    o.z = pack2(b.x, b.y);
    o.w = pack2(b.z, b.w);
    *((uint4*)out + i) = o;
}

// ---------------------------------------------------------------------------
// transpose + convert: out[c*R + r] = bf16(in[r*C + c])
// ---------------------------------------------------------------------------
__global__ void transpose_cvt(const float* __restrict__ in, uint16_t* __restrict__ out,
                              int R, int C) {
    int idx = blockIdx.x * 256 + threadIdx.x;
    if (idx >= R * C) return;
    int r = idx / C;
    int c = idx - r * C;
    out[(size_t)c * R + r] = f2bf(in[idx]);
}

// ---------------------------------------------------------------------------
// m97-style bf16 GEMM: C[M,N] = A[M,K] @ B[K,N], B given transposed (BT[N,K]).
// 128x128 tile, BK=32, 256 threads (4 waves, each 64x64 = 4x4 mfma 16x16x32).
// F32OUT: store fp32 instead of bf16.
// ---------------------------------------------------------------------------
template <bool F32OUT>
__global__ __launch_bounds__(256, 2)
void gemm_bt(const uint16_t* __restrict__ A, const uint16_t* __restrict__ BT,
             void* __restrict__ Cout, int M, int N, int K) {
    __shared__ __align__(16) uint16_t As[128 * 32];
    __shared__ __align__(16) uint16_t Bs[128 * 32];

    const int tid  = threadIdx.x;
    const int lane = tid & 63;
    const int wv   = tid >> 6;
    const int r    = lane & 15;
    const int quad = lane >> 4;
    const int m_w  = (wv & 1) << 6;
    const int n_w  = (wv >> 1) << 6;
    const long bm0 = (long)blockIdx.x * 128;
    const long bn0 = (long)blockIdx.y * 128;

    f32x4 acc[4][4];
#pragma unroll
    for (int i = 0; i < 4; ++i)
#pragma unroll
        for (int j = 0; j < 4; ++j) acc[i][j] = (f32x4){0.f, 0.f, 0.f, 0.f};

    const int c0 = tid, c1 = tid + 256;
    const uint16_t* pA0 = A + (bm0 + (c0 >> 2)) * (long)K + (c0 & 3) * 8;
    const uint16_t* pA1 = A + (bm0 + (c1 >> 2)) * (long)K + (c1 & 3) * 8;
    const uint16_t* pB0 = BT + (bn0 + (c0 >> 2)) * (long)K + (c0 & 3) * 8;
    const uint16_t* pB1 = BT + (bn0 + (c1 >> 2)) * (long)K + (c1 & 3) * 8;

    for (int kt = 0; kt < K; kt += 32) {
        GLOAD_LDS16(pA0 + kt, &As[c0 * 8]);
        GLOAD_LDS16(pA1 + kt, &As[c1 * 8]);
        GLOAD_LDS16(pB0 + kt, &Bs[c0 * 8]);
        GLOAD_LDS16(pB1 + kt, &Bs[c1 * 8]);
        __syncthreads();

        bf16x8 af[4], bf[4];
#pragma unroll
        for (int mt = 0; mt < 4; ++mt)
            af[mt] = *(const bf16x8*)&As[(m_w + mt * 16 + r) * 32 + quad * 8];
#pragma unroll
        for (int nt = 0; nt < 4; ++nt)
            bf[nt] = *(const bf16x8*)&Bs[(n_w + nt * 16 + r) * 32 + quad * 8];
#pragma unroll
        for (int mt = 0; mt < 4; ++mt)
#pragma unroll
            for (int nt = 0; nt < 4; ++nt)
                acc[mt][nt] = __builtin_amdgcn_mfma_f32_16x16x32_bf16(af[mt], bf[nt],
                                                                      acc[mt][nt], 0, 0, 0);
        __syncthreads();
    }

    // D[row = quad*4 + i][col = lane&15]
#pragma unroll
    for (int mt = 0; mt < 4; ++mt) {
#pragma unroll
        for (int i = 0; i < 4; ++i) {
            long m = bm0 + m_w + mt * 16 + quad * 4 + i;
            if (F32OUT) {
                float* crow = (float*)Cout + m * (long)N + bn0 + n_w + r;
#pragma unroll
                for (int nt = 0; nt < 4; ++nt) crow[nt * 16] = acc[mt][nt][i];
            } else {
                uint16_t* crow = (uint16_t*)Cout + m * (long)N + bn0 + n_w + r;
#pragma unroll
                for (int nt = 0; nt < 4; ++nt) crow[nt * 16] = f2bf(acc[mt][nt][i]);
            }
        }
    }
}

// ---------------------------------------------------------------------------
// Local window attention. Block = (bn, head); thread = s (256 threads).
// qkv row layout: [q(512) | k(512) | v(512)] bf16, head slice h*64.
// Padded window entries: score = 0*scale + bias (IN softmax), v contributes 0.
// pos_bias is fp32 [8][256][7].
// ---------------------------------------------------------------------------
__global__ __launch_bounds__(256, 4)
void local_attn(const uint16_t* __restrict__ qkv, const float* __restrict__ pb,
                uint16_t* __restrict__ attn) {
    const int h  = blockIdx.x & 7;
    const int bn = blockIdx.x >> 3;
    const int s  = threadIdx.x;
    const size_t base = (size_t)bn * 256 * 1536;

    const uint16_t* qrow = qkv + base + (size_t)s * 1536 + h * 64;

    float sc[7];
#pragma unroll
    for (int w = 0; w < 7; ++w) sc[w] = 0.f;

#pragma unroll
    for (int c = 0; c < 8; ++c) {
        uint4 qc = *(const uint4*)(qrow + c * 8);
        float qf[8];
        unpack8(qc, qf);
#pragma unroll
        for (int w = 0; w < 7; ++w) {
            int sp = s + w - 3;
            if ((unsigned)sp < 256u) {
                const uint16_t* krow = qkv + base + (size_t)sp * 1536 + 512 + h * 64;
                uint4 kc = *(const uint4*)(krow + c * 8);
                float kf[8];
                unpack8(kc, kf);
#pragma unroll
                for (int j = 0; j < 8; ++j) sc[w] += qf[j] * kf[j];
            }
        }
    }

    const float* pbr = pb + ((size_t)h * 256 + s) * 7;
    float mx = -1e30f;
#pragma unroll
    for (int w = 0; w < 7; ++w) {
        sc[w] = sc[w] * 0.125f + pbr[w];
        mx = fmaxf(mx, sc[w]);
    }
    float p[7], sum = 0.f;
#pragma unroll
    for (int w = 0; w < 7; ++w) {
        p[w] = __expf(sc[w] - mx);
        sum += p[w];
    }
    const float inv = 1.f / sum;

    uint16_t* orow = attn + ((size_t)(bn * 256 + s)) * 512 + h * 64;
#pragma unroll
    for (int c = 0; c < 8; ++c) {
        float o[8] = {0.f, 0.f, 0.f, 0.f, 0.f, 0.f, 0.f, 0.f};
#pragma unroll
        for (int w = 0; w < 7; ++w) {
            int sp = s + w - 3;
            if ((unsigned)sp < 256u) {
                const uint16_t* vrow = qkv + base + (size_t)sp * 1536 + 1024 + h * 64;
                uint4 vc = *(const uint4*)(vrow + c * 8);
                float vf[8];
                unpack8(vc, vf);
                float pw = p[w] * inv;
#pragma unroll
                for (int j = 0; j < 8; ++j) o[j] += pw * vf[j];
            }
        }
        uint4 ov;
        ov.x = pack2(o[0], o[1]);
        ov.y = pack2(o[2], o[3]);
        ov.z = pack2(o[4], o[5]);
        ov.w = pack2(o[6], o[7]);
        *(uint4*)(orow + c * 8) = ov;
    }
}

// ---------------------------------------------------------------------------
extern "C" void kernel_launch(void* const* d_in, const int* in_sizes, int n_in,
                              void* d_out, int out_size, void* d_ws, size_t ws_size,
                              hipStream_t stream) {
    const float* X    = (const float*)d_in[0];  // 32768 x 512 fp32
    const float* pb   = (const float*)d_in[1];  // 8 x 256 x 7 fp32
    const float* Wqkv = (const float*)d_in[2];  // 512 x 1536 fp32
    const float* Wout = (const float*)d_in[3];  // 512 x 512 fp32
    float* out = (float*)d_out;                 // 32768 x 512 fp32

    char* ws = (char*)d_ws;
    uint16_t* WqkvT = (uint16_t*)(ws);                  // 1536x512 bf16 = 1.5 MB
    uint16_t* WoutT = (uint16_t*)(ws + 1572864);        // 512x512  bf16 = 0.5 MB
    uint16_t* qkvb  = (uint16_t*)(ws + 2097152);        // 32768x1536 bf16 = 96 MB
    uint16_t* Xb    = (uint16_t*)(ws + 102760448);      // 32768x512 bf16 = 32 MB
    uint16_t* attnb = Xb;  // alias: Xb dead after GEMM1 (stream-ordered)

    cvt_f32_bf16<<<(32768 * 512 / 8 + 255) / 256, 256, 0, stream>>>(X, Xb, 32768 * 512 / 8);
    transpose_cvt<<<(512 * 1536 + 255) / 256, 256, 0, stream>>>(Wqkv, WqkvT, 512, 1536);
    transpose_cvt<<<(512 * 512 + 255) / 256, 256, 0, stream>>>(Wout, WoutT, 512, 512);

    gemm_bt<false><<<dim3(256, 12), 256, 0, stream>>>(Xb, WqkvT, qkvb, 32768, 1536, 512);
    local_attn<<<1024, 256, 0, stream>>>(qkvb, pb, attnb);
    gemm_bt<true><<<dim3(256, 4), 256, 0, stream>>>(attnb, WoutT, out, 32768, 512, 512);
}

// Round 3
// 267.303 us; speedup vs baseline: 2.2903x; 2.2903x over previous
//
#include <hip/hip_runtime.h>
#include <hip/hip_bf16.h>
#include <cstdint>

// B=2, HW=64 -> 128 rows of S=256; M = 32768. D=512, HEADS=8, DK=64,
// 3*H*DK=1536, KSIZE=7. Inputs/outputs are float32 on device (per reference);
// internal compute uses bf16 MFMA (2%-relative threshold permits it).

typedef __bf16 bf16x8 __attribute__((ext_vector_type(8)));
typedef float f32x4 __attribute__((ext_vector_type(4)));

__device__ __forceinline__ uint16_t f2bf(float f) {
    uint32_t u = __builtin_bit_cast(uint32_t, f);
    return (uint16_t)((u + 0x7fffu + ((u >> 16) & 1u)) >> 16);
}
__device__ __forceinline__ float bflo(uint32_t u) { return __builtin_bit_cast(float, u << 16); }
__device__ __forceinline__ float bfhi(uint32_t u) { return __builtin_bit_cast(float, u & 0xffff0000u); }

__device__ __forceinline__ void unpack8(uint4 v, float* f) {
    f[0] = bflo(v.x); f[1] = bfhi(v.x);
    f[2] = bflo(v.y); f[3] = bfhi(v.y);
    f[4] = bflo(v.z); f[5] = bfhi(v.z);
    f[6] = bflo(v.w); f[7] = bfhi(v.w);
}
__device__ __forceinline__ uint32_t pack2(float a, float b) {
    return (uint32_t)f2bf(a) | ((uint32_t)f2bf(b) << 16);
}

#define GLOAD_LDS16(gp, lp)                                                        \
    __builtin_amdgcn_global_load_lds((const __attribute__((address_space(1))) void*)(gp), \
                                     (__attribute__((address_space(3))) void*)(lp), 16, 0, 0)

// ---------------------------------------------------------------------------
// fp32 -> bf16 bulk convert, 8 elems/thread
// ---------------------------------------------------------------------------
__global__ void cvt_f32_bf16(const float* __restrict__ in, uint16_t* __restrict__ out, int n8) {
    int i = blockIdx.x * 256 + threadIdx.x;
    if (i >= n8) return;
    const float4* p = (const float4*)in + (size_t)i * 2;
    float4 a = p[0], b = p[1];
    uint4 o;
    o.x = pack2(a.x, a.y);
    o.y = pack2(a.z, a.w);
    o.z = pack2(b.x, b.y);
    o.w = pack2(b.z, b.w);
    *((uint4*)out + i) = o;
}

// ---------------------------------------------------------------------------
// transpose + convert: out[c*R + r] = bf16(in[r*C + c])
// ---------------------------------------------------------------------------
__global__ void transpose_cvt(const float* __restrict__ in, uint16_t* __restrict__ out,
                              int R, int C) {
    int idx = blockIdx.x * 256 + threadIdx.x;
    if (idx >= R * C) return;
    int r = idx / C;
    int c = idx - r * C;
    out[(size_t)c * R + r] = f2bf(in[idx]);
}

// ---------------------------------------------------------------------------
// m97-style bf16 GEMM: C[M,N] = A[M,K] @ B[K,N], B given transposed (BT[N,K]).
// 128x128 tile, BK=32, 256 threads (4 waves, each 64x64 = 4x4 mfma 16x16x32).
// F32OUT: store fp32 instead of bf16.
// ---------------------------------------------------------------------------
template <bool F32OUT>
__global__ __launch_bounds__(256, 2)
void gemm_bt(const uint16_t* __restrict__ A, const uint16_t* __restrict__ BT,
             void* __restrict__ Cout, int M, int N, int K) {
    __shared__ __align__(16) uint16_t As[128 * 32];
    __shared__ __align__(16) uint16_t Bs[128 * 32];

    const int tid  = threadIdx.x;
    const int lane = tid & 63;
    const int wv   = tid >> 6;
    const int r    = lane & 15;
    const int quad = lane >> 4;
    const int m_w  = (wv & 1) << 6;
    const int n_w  = (wv >> 1) << 6;
    const long bm0 = (long)blockIdx.x * 128;
    const long bn0 = (long)blockIdx.y * 128;

    f32x4 acc[4][4];
#pragma unroll
    for (int i = 0; i < 4; ++i)
#pragma unroll
        for (int j = 0; j < 4; ++j) acc[i][j] = (f32x4){0.f, 0.f, 0.f, 0.f};

    const int c0 = tid, c1 = tid + 256;
    const uint16_t* pA0 = A + (bm0 + (c0 >> 2)) * (long)K + (c0 & 3) * 8;
    const uint16_t* pA1 = A + (bm0 + (c1 >> 2)) * (long)K + (c1 & 3) * 8;
    const uint16_t* pB0 = BT + (bn0 + (c0 >> 2)) * (long)K + (c0 & 3) * 8;
    const uint16_t* pB1 = BT + (bn0 + (c1 >> 2)) * (long)K + (c1 & 3) * 8;

    for (int kt = 0; kt < K; kt += 32) {
        GLOAD_LDS16(pA0 + kt, &As[c0 * 8]);
        GLOAD_LDS16(pA1 + kt, &As[c1 * 8]);
        GLOAD_LDS16(pB0 + kt, &Bs[c0 * 8]);
        GLOAD_LDS16(pB1 + kt, &Bs[c1 * 8]);
        __syncthreads();

        bf16x8 af[4], bf[4];
#pragma unroll
        for (int mt = 0; mt < 4; ++mt)
            af[mt] = *(const bf16x8*)&As[(m_w + mt * 16 + r) * 32 + quad * 8];
#pragma unroll
        for (int nt = 0; nt < 4; ++nt)
            bf[nt] = *(const bf16x8*)&Bs[(n_w + nt * 16 + r) * 32 + quad * 8];
#pragma unroll
        for (int mt = 0; mt < 4; ++mt)
#pragma unroll
            for (int nt = 0; nt < 4; ++nt)
                acc[mt][nt] = __builtin_amdgcn_mfma_f32_16x16x32_bf16(af[mt], bf[nt],
                                                                      acc[mt][nt], 0, 0, 0);
        __syncthreads();
    }

    // D[row = quad*4 + i][col = lane&15]
#pragma unroll
    for (int mt = 0; mt < 4; ++mt) {
#pragma unroll
        for (int i = 0; i < 4; ++i) {
            long m = bm0 + m_w + mt * 16 + quad * 4 + i;
            if (F32OUT) {
                float* crow = (float*)Cout + m * (long)N + bn0 + n_w + r;
#pragma unroll
                for (int nt = 0; nt < 4; ++nt) crow[nt * 16] = acc[mt][nt][i];
            } else {
                uint16_t* crow = (uint16_t*)Cout + m * (long)N + bn0 + n_w + r;
#pragma unroll
                for (int nt = 0; nt < 4; ++nt) crow[nt * 16] = f2bf(acc[mt][nt][i]);
            }
        }
    }
}

// ---------------------------------------------------------------------------
// Local window attention, LDS-staged K/V.
// Block = (bn, head), 256 threads, thread = s.
// LDS: K tile + V tile = 2 * 256 rows * 64 elems * 2B = 64 KB (2 blocks/CU).
// 16-B chunk column is XOR-swizzled by (sp&7) -> conflict-free for the
// stride-128B compute-phase reads without padding bytes.
// Q is per-thread (read once from global, full cache-line use) in registers.
// Padded window entries (sp out of range): score = bias only, v contributes 0.
// ---------------------------------------------------------------------------
__global__ __launch_bounds__(256, 2)
void local_attn(const uint16_t* __restrict__ qkv, const float* __restrict__ pb,
                uint16_t* __restrict__ attn) {
    __shared__ uint4 smem[4096];  // [0,2048): K chunks, [2048,4096): V chunks

    const int h  = blockIdx.x & 7;
    const int bn = blockIdx.x >> 3;
    const int s  = threadIdx.x;
    const size_t base = (size_t)bn * 256 * 1536;

    // ---- stage K,V: 4096 16-B chunks, 16 per thread, coalesced ----
#pragma unroll
    for (int it = 0; it < 16; ++it) {
        int i   = threadIdx.x + it * 256;
        int a   = i >> 11;        // 0=K, 1=V
        int idx = i & 2047;
        int sp  = idx >> 3;
        int c8  = idx & 7;
        const uint16_t* src = qkv + base + (size_t)sp * 1536 + 512 + a * 512 + h * 64 + c8 * 8;
        smem[a * 2048 + sp * 8 + (c8 ^ (sp & 7))] = *(const uint4*)src;
    }

    // ---- load own Q row into registers (8 x 16B = 128 B) ----
    const uint16_t* qrow = qkv + base + (size_t)s * 1536 + h * 64;
    uint4 qc[8];
#pragma unroll
    for (int c = 0; c < 8; ++c) qc[c] = *(const uint4*)(qrow + c * 8);

    __syncthreads();

    // ---- scores ----
    float sc[7];
#pragma unroll
    for (int w = 0; w < 7; ++w) sc[w] = 0.f;

#pragma unroll
    for (int c = 0; c < 8; ++c) {
        float qf[8];
        unpack8(qc[c], qf);
#pragma unroll
        for (int w = 0; w < 7; ++w) {
            int sp = s + w - 3;
            if ((unsigned)sp < 256u) {
                uint4 kc = smem[sp * 8 + (c ^ (sp & 7))];
                float kf[8];
                unpack8(kc, kf);
#pragma unroll
                for (int j = 0; j < 8; ++j) sc[w] += qf[j] * kf[j];
            }
        }
    }

    const float* pbr = pb + ((size_t)h * 256 + s) * 7;
    float mx = -1e30f;
#pragma unroll
    for (int w = 0; w < 7; ++w) {
        sc[w] = sc[w] * 0.125f + pbr[w];
        mx = fmaxf(mx, sc[w]);
    }
    float p[7], sum = 0.f;
#pragma unroll
    for (int w = 0; w < 7; ++w) {
        p[w] = __expf(sc[w] - mx);
        sum += p[w];
    }
    const float inv = 1.f / sum;
#pragma unroll
    for (int w = 0; w < 7; ++w) p[w] *= inv;

    // ---- output: accumulate all 64 elems in regs, then one contiguous 128-B store ----
    uint4 ov[8];
#pragma unroll
    for (int c = 0; c < 8; ++c) {
        float o[8] = {0.f, 0.f, 0.f, 0.f, 0.f, 0.f, 0.f, 0.f};
#pragma unroll
        for (int w = 0; w < 7; ++w) {
            int sp = s + w - 3;
            if ((unsigned)sp < 256u) {
                uint4 vc = smem[2048 + sp * 8 + (c ^ (sp & 7))];
                float vf[8];
                unpack8(vc, vf);
#pragma unroll
                for (int j = 0; j < 8; ++j) o[j] += p[w] * vf[j];
            }
        }
        ov[c].x = pack2(o[0], o[1]);
        ov[c].y = pack2(o[2], o[3]);
        ov[c].z = pack2(o[4], o[5]);
        ov[c].w = pack2(o[6], o[7]);
    }

    uint16_t* orow = attn + ((size_t)(bn * 256 + s)) * 512 + h * 64;
#pragma unroll
    for (int c = 0; c < 8; ++c) *(uint4*)(orow + c * 8) = ov[c];
}

// ---------------------------------------------------------------------------
extern "C" void kernel_launch(void* const* d_in, const int* in_sizes, int n_in,
                              void* d_out, int out_size, void* d_ws, size_t ws_size,
                              hipStream_t stream) {
    const float* X    = (const float*)d_in[0];  // 32768 x 512 fp32
    const float* pb   = (const float*)d_in[1];  // 8 x 256 x 7 fp32
    const float* Wqkv = (const float*)d_in[2];  // 512 x 1536 fp32
    const float* Wout = (const float*)d_in[3];  // 512 x 512 fp32
    float* out = (float*)d_out;                 // 32768 x 512 fp32

    char* ws = (char*)d_ws;
    uint16_t* WqkvT = (uint16_t*)(ws);                  // 1536x512 bf16 = 1.5 MB
    uint16_t* WoutT = (uint16_t*)(ws + 1572864);        // 512x512  bf16 = 0.5 MB
    uint16_t* qkvb  = (uint16_t*)(ws + 2097152);        // 32768x1536 bf16 = 96 MB
    uint16_t* Xb    = (uint16_t*)(ws + 102760448);      // 32768x512 bf16 = 32 MB
    uint16_t* attnb = Xb;  // alias: Xb dead after GEMM1 (stream-ordered)

    cvt_f32_bf16<<<(32768 * 512 / 8 + 255) / 256, 256, 0, stream>>>(X, Xb, 32768 * 512 / 8);
    transpose_cvt<<<(512 * 1536 + 255) / 256, 256, 0, stream>>>(Wqkv, WqkvT, 512, 1536);
    transpose_cvt<<<(512 * 512 + 255) / 256, 256, 0, stream>>>(Wout, WoutT, 512, 512);

    gemm_bt<false><<<dim3(256, 12), 256, 0, stream>>>(Xb, WqkvT, qkvb, 32768, 1536, 512);
    local_attn<<<1024, 256, 0, stream>>>(qkvb, pb, attnb);
    gemm_bt<true><<<dim3(256, 4), 256, 0, stream>>>(attnb, WoutT, out, 32768, 512, 512);
}